// Round 9
// baseline (3713.458 us; speedup 1.0000x reference)
//
#include <hip/hip_runtime.h>
#include <math.h>

typedef unsigned long long ull;

constexpr int Bn = 32, Tn = 64, Hn = 320, Jn = 320, Vn = 1024, Sn = 128;
constexpr int G4n = 1280, VP1 = 1025, WO4S = 1028;

// workspace layout (float units) -- ~11.5 MB total
constexpr int OFF_XP   = 0;                       // 32*64*320
constexpr int OFF_G    = OFF_XP + Bn*Tn*Jn;       // 1024*1280
constexpr int OFF_WO4  = OFF_G + Vn*G4n;          // 80*1028*4
constexpr int OFF_WH4  = OFF_WO4 + 80*WO4S*4;     // 80*1280*4
constexpr int OFF_WP4  = OFF_WH4 + 80*G4n*4;      // 80*320*4
constexpr int OFF_RECF = OFF_WP4 + 80*Jn*4;       // 32*320 (f records)
constexpr int OFF_RECG = OFF_RECF + Bn*Jn;        // 32*1280 (gg records)
constexpr int OFF_KEY  = OFF_RECG + Bn*G4n;       // 32 groups * 64 ull = 4096 f32
constexpr int OFF_FLG  = OFF_KEY + 4096;          // 32*8*16 ints = 4096

#define AL(p)    __hip_atomic_load((p), __ATOMIC_RELAXED, __HIP_MEMORY_SCOPE_AGENT)
#define AS(p, v) __hip_atomic_store((p), (v), __ATOMIC_RELAXED, __HIP_MEMORY_SCOPE_AGENT)

__device__ __forceinline__ float sigmf(float x) { return 1.0f / (1.0f + expf(-x)); }

// key = mapped_val(32) | epoch(21 bits) | (2047-idx)(11 bits)
__device__ __forceinline__ ull pack_key_e(float v, int idx, int es) {
    unsigned u = __float_as_uint(v);
    u = (u & 0x80000000u) ? ~u : (u | 0x80000000u);
    return ((ull)u << 32) | ((ull)(unsigned)es << 11) | (unsigned)(2047 - idx);
}
__device__ __forceinline__ float key_val_e(ull k) {
    unsigned u = (unsigned)(k >> 32);
    return __uint_as_float((u & 0x80000000u) ? (u & 0x7FFFFFFFu) : ~u);
}
__device__ __forceinline__ int key_idx_e(ull k) { return 2047 - (int)(k & 0x7FF); }
__device__ __forceinline__ int key_ep_e(ull k)  { return (int)((k >> 11) & 0x1FFFFF); }

// ---------------- generic tiled f32 GEMM: C = A@B + bias ----------------
__global__ __launch_bounds__(256) void gemm_bias(const float* __restrict__ A,
                                                 const float* __restrict__ Bm,
                                                 const float* __restrict__ bias,
                                                 float* __restrict__ C,
                                                 int M, int N, int K) {
    __shared__ float As[16][65];
    __shared__ float Bs[16][65];
    const int tx = threadIdx.x & 15, ty = threadIdx.x >> 4;
    const int n0 = blockIdx.x * 64, m0 = blockIdx.y * 64;
    float acc[4][4] = {};
    for (int k0 = 0; k0 < K; k0 += 16) {
        for (int i = threadIdx.x; i < 1024; i += 256) {
            int mm = i >> 4, kk = i & 15;
            As[kk][mm] = A[(m0 + mm) * K + k0 + kk];
            int kk2 = i >> 6, nn = i & 63;
            Bs[kk2][nn] = Bm[(k0 + kk2) * N + n0 + nn];
        }
        __syncthreads();
#pragma unroll
        for (int kk = 0; kk < 16; ++kk) {
            float av[4], bv[4];
#pragma unroll
            for (int r = 0; r < 4; ++r) { av[r] = As[kk][ty * 4 + r]; bv[r] = Bs[kk][tx * 4 + r]; }
#pragma unroll
            for (int i2 = 0; i2 < 4; ++i2)
#pragma unroll
                for (int j2 = 0; j2 < 4; ++j2) acc[i2][j2] += av[i2] * bv[j2];
        }
        __syncthreads();
    }
#pragma unroll
    for (int i2 = 0; i2 < 4; ++i2)
#pragma unroll
        for (int j2 = 0; j2 < 4; ++j2)
            C[(m0 + ty * 4 + i2) * N + n0 + tx * 4 + j2] = acc[i2][j2] + bias[n0 + tx * 4 + j2];
}

// ---------------- k4-interleave repacks: W4[k/4][col][4] = W[k][col] ----------------
__global__ __launch_bounds__(256) void repack_wout4(const float* __restrict__ W,
                                                    float* __restrict__ W4) {
    const int k4 = blockIdx.x;
    for (int c = threadIdx.x; c < VP1; c += 256) {
        float4 v;
        v.x = W[(k4 * 4 + 0) * VP1 + c];
        v.y = W[(k4 * 4 + 1) * VP1 + c];
        v.z = W[(k4 * 4 + 2) * VP1 + c];
        v.w = W[(k4 * 4 + 3) * VP1 + c];
        ((float4*)W4)[(size_t)k4 * WO4S + c] = v;
    }
}
__global__ __launch_bounds__(256) void repack_whh4(const float* __restrict__ W,
                                                   float* __restrict__ W4) {
    const int k4 = blockIdx.x;
    for (int c = threadIdx.x; c < G4n; c += 256) {
        float4 v;
        v.x = W[(k4 * 4 + 0) * G4n + c];
        v.y = W[(k4 * 4 + 1) * G4n + c];
        v.z = W[(k4 * 4 + 2) * G4n + c];
        v.w = W[(k4 * 4 + 3) * G4n + c];
        ((float4*)W4)[(size_t)k4 * G4n + c] = v;
    }
}
__global__ __launch_bounds__(256) void repack_wpred4(const float* __restrict__ W,
                                                     float* __restrict__ W4) {
    const int k4 = blockIdx.x;
    for (int c = threadIdx.x; c < Jn; c += 256) {
        float4 v;
        v.x = W[(k4 * 4 + 0) * Jn + c];
        v.y = W[(k4 * 4 + 1) * Jn + c];
        v.z = W[(k4 * 4 + 2) * Jn + c];
        v.w = W[(k4 * 4 + 3) * Jn + c];
        ((float4*)W4)[(size_t)k4 * Jn + c] = v;
    }
}

// ---------------- decode: 8 WGs per batch element, fat-record dataflow ----------------
__global__ __launch_bounds__(256, 1) void rnnt_decode(
    const float* __restrict__ xp, const float* __restrict__ Gm,
    const float* __restrict__ Wo4, const float* __restrict__ Wh4,
    const float* __restrict__ Wp4,
    const float* __restrict__ b_out, const float* __restrict__ b_lstm,
    const float* __restrict__ b_pred, const int* __restrict__ out_len,
    float* __restrict__ recF, float* __restrict__ recG, ull* __restrict__ keyG,
    int* __restrict__ flgG, float* __restrict__ out) {
    __shared__ __align__(16) ull fs8_[160];     // f (320 f32)
    float* f_s = (float*)fs8_;
    __shared__ __align__(16) ull gg8_[640];     // gates (1280 f32)
    float* gg_s = (float*)gg8_;
    __shared__ __align__(16) float h_s[Hn];
    __shared__ float c_s[Hn];
    __shared__ float dec_s[40];
    __shared__ float xpA[40], xpB[40];
    __shared__ ull bk_s;

    const int w = blockIdx.x, tid = threadIdx.x;
    const int b = w & 31, m = w >> 5;
    const int ol = out_len[b];
    const float* xpb = xp + b * Tn * Jn;
    ull*  recF8 = (ull*)(recF + b * Jn);
    ull*  recG8 = (ull*)(recG + b * G4n);
    ull*  keysb = keyG + b * 64;             // slots 0..31 member keys, 32 blank
    int*  flgb  = flgG + b * 128;            // member m flag at m*16

    const float4* Wo4f = (const float4*)Wo4;
    const float4* Wh4f = (const float4*)Wh4;
    const float4* Wp4f = (const float4*)Wp4;
    const float4* h4 = (const float4*)h_s;
    const float4* f4 = (const float4*)f_s;

    // ==== prologue (replicated): h0, c0, full dec0 -> f0; own slices published ====
    for (int r = tid; r < Hn; r += 256) {
        float c0 = sigmf(b_lstm[r]) * tanhf(b_lstm[2 * Hn + r]);
        float h0 = sigmf(b_lstm[3 * Hn + r]) * tanhf(c0);
        c_s[r] = c0; h_s[r] = h0;
    }
    __syncthreads();
    for (int c = tid; c < Jn; c += 256) {
        float ax = 0.f, ay = 0.f, az = 0.f, aw = 0.f;
#pragma unroll 10
        for (int k4 = 0; k4 < 80; ++k4) {
            float4 wv = Wp4f[(size_t)k4 * Jn + c];
            float4 hv = h4[k4];
            ax += wv.x * hv.x; ay += wv.y * hv.y;
            az += wv.z * hv.z; aw += wv.w * hv.w;
        }
        float d = b_pred[c] + ax + ay + az + aw;
        float fv = xpb[c] + d;
        f_s[c] = fv > 0.0f ? fv : 0.0f;
        int lc = c - m * 40;
        if (lc >= 0 && lc < 40) dec_s[lc] = d;
    }
    if (tid < 160) {   // gg0 own slice
        const int c = m * 160 + tid;
        float ax = 0.f, ay = 0.f, az = 0.f, aw = 0.f;
#pragma unroll 10
        for (int k4 = 0; k4 < 80; ++k4) {
            float4 wv = Wh4f[(size_t)k4 * G4n + c];
            float4 hv = h4[k4];
            ax += wv.x * hv.x; ay += wv.y * hv.y;
            az += wv.z * hv.z; aw += wv.w * hv.w;
        }
        gg_s[c] = ax + ay + az + aw;
    }
    __syncthreads();
    if (tid < 20)  AS(recF8 + m * 20 + tid, ((ull*)(f_s + m * 40))[tid]);
    if (tid < 80)  AS(recG8 + m * 80 + tid, ((ull*)(gg_s + m * 160))[tid]);
    __syncthreads();   // drains vmcnt on all waves
    if (tid == 0) AS(flgb + m * 16, 1);

    // ==== step loop ====
    int told = 0, sold = 0, lenacc = 0;
    bool prevEmit = true;
    int s = 0;
    for (; s < Sn; ++s) {
        if (told >= ol) break;
        const int es = s + 1;
        // ---- 1: poll release flags, batch-read records ----
        if (tid < 8) {
            while (AL(flgb + tid * 16) < es) __builtin_amdgcn_s_sleep(1);
        }
        __syncthreads();
        if (tid < 160) fs8_[tid] = AL(recF8 + tid);
        if (prevEmit) {
            gg8_[tid]       = AL(recG8 + tid);
            gg8_[tid + 256] = AL(recG8 + tid + 256);
            if (tid < 128) gg8_[tid + 512] = AL(recG8 + tid + 512);
        }
        // xp prefetch for both tnew candidates
        {
            const int tA = told, tB = (told + 1 < Tn - 1) ? told + 1 : Tn - 1;
            if (tid < 40) xpA[tid] = xpb[tA * Jn + m * 40 + tid];
            else if (tid >= 64 && tid < 104) xpB[tid - 64] = xpb[tB * Jn + m * 40 + tid - 64];
        }
        __syncthreads();
        // ---- 2: logits (all 4 waves; 2 threads/col, k-split) + keys ----
        {
            const int cl = tid >> 1, kh = tid & 1;
            const int c = m * 128 + cl;
            float ax = 0.f, ay = 0.f, az = 0.f, aw = 0.f;
#pragma unroll 10
            for (int k4 = kh * 40; k4 < kh * 40 + 40; ++k4) {
                float4 wv = Wo4f[(size_t)k4 * WO4S + c];
                float4 fv = f4[k4];
                ax += wv.x * fv.x; ay += wv.y * fv.y;
                az += wv.z * fv.z; aw += wv.w * fv.w;
            }
            float part = ax + ay + az + aw;
            part += __shfl_xor(part, 1, 64);
            ull key = pack_key_e(part + b_out[c], c, es);
#pragma unroll
            for (int d = 1; d < 64; d <<= 1) {
                ull o = __shfl_xor(key, d, 64);
                if (o > key) key = o;
            }
            if ((tid & 63) == 0) AS(keysb + m * 4 + (tid >> 6), key);
            if (m == 7 && tid < 64) {   // blank column 1024 on wave 0
                float4 wv = Wo4f[(size_t)tid * WO4S + Vn];
                float4 fv = f4[tid];
                float p = wv.x * fv.x + wv.y * fv.y + wv.z * fv.z + wv.w * fv.w;
                if (tid < 16) {
                    float4 wv2 = Wo4f[(size_t)(64 + tid) * WO4S + Vn];
                    float4 fv2 = f4[64 + tid];
                    p += wv2.x * fv2.x + wv2.y * fv2.y + wv2.z * fv2.z + wv2.w * fv2.w;
                }
#pragma unroll
                for (int d = 1; d < 64; d <<= 1) p += __shfl_xor(p, d, 64);
                if (tid == 0) AS(keysb + 32, pack_key_e(p + b_out[Vn], Vn, es));
            }
        }
        // ---- 3: key poll + reduce (wave 0) ----
        if (tid < 64) {
            ull k = 0;
            if (tid < 33) {
                do {
                    k = AL(keysb + tid);
                    if (key_ep_e(k) >= es) break;
                    __builtin_amdgcn_s_sleep(1);
                } while (true);
            }
#pragma unroll
            for (int d = 1; d < 64; d <<= 1) {
                ull o = __shfl_xor(k, d, 64);
                if (o > k) k = o;
            }
            if (tid == 0) bk_s = k;
        }
        __syncthreads();
        // ---- 4: decode logic (replicated) ----
        const ull bk = bk_s;
        const int label = key_idx_e(bk);
        const bool emit = (label != Vn);
        int sym2 = emit ? sold + 1 : 0;
        const bool force = emit && (sym2 >= 2);
        const bool advance = (!emit) || force;
        const int tnew = told + (advance ? 1 : 0);
        sym2 = advance ? 0 : sym2;
        if (m == 0 && tid == 0) {
            out[s * Bn + b] = emit ? (float)label : 1024.0f;
            out[Sn * Bn + s * Bn + b] = key_val_e(bk);
            out[2 * Sn * Bn + s * Bn + b] = (float)told;
            if (emit) lenacc++;
        }
        // ---- 5: emit path: LSTM -> dec slice + gates slice ----
        if (emit) {
            const float* gE = Gm + (size_t)label * G4n;
#pragma unroll 2
            for (int rr = 0; rr < 2; ++rr) {
                int r = tid + rr * 256;
                if (r < Hn) {
                    float xi = gg_s[r]          + gE[r];
                    float xf = gg_s[Hn + r]     + gE[Hn + r];
                    float xg = gg_s[2 * Hn + r] + gE[2 * Hn + r];
                    float xo = gg_s[3 * Hn + r] + gE[3 * Hn + r];
                    float c2 = sigmf(xf) * c_s[r] + sigmf(xi) * tanhf(xg);
                    float h2 = sigmf(xo) * tanhf(c2);
                    c_s[r] = c2; h_s[r] = h2;
                }
            }
            __syncthreads();   // h_s complete
            if (tid < 80) {
                // dec slice: 2 threads per col, k-split
                const int cl = tid >> 1, kh = tid & 1;
                const int c = m * 40 + cl;
                float ax = 0.f, ay = 0.f, az = 0.f, aw = 0.f;
#pragma unroll 10
                for (int k4 = kh * 40; k4 < kh * 40 + 40; ++k4) {
                    float4 wv = Wp4f[(size_t)k4 * Jn + c];
                    float4 hv = h4[k4];
                    ax += wv.x * hv.x; ay += wv.y * hv.y;
                    az += wv.z * hv.z; aw += wv.w * hv.w;
                }
                float part = ax + ay + az + aw;
                part += __shfl_xor(part, 1, 64);
                if (kh == 0) dec_s[cl] = part + b_pred[c];
            } else if (tid >= 128) {
                // gates slice: 160 cols on waves 2-3
                int c1 = tid - 128;
                {
                    const int c = m * 160 + c1;
                    float ax = 0.f, ay = 0.f, az = 0.f, aw = 0.f;
#pragma unroll 10
                    for (int k4 = 0; k4 < 80; ++k4) {
                        float4 wv = Wh4f[(size_t)k4 * G4n + c];
                        float4 hv = h4[k4];
                        ax += wv.x * hv.x; ay += wv.y * hv.y;
                        az += wv.z * hv.z; aw += wv.w * hv.w;
                    }
                    gg_s[c] = ax + ay + az + aw;
                }
                if (c1 < 32) {
                    const int c = m * 160 + 128 + c1;
                    float ax = 0.f, ay = 0.f, az = 0.f, aw = 0.f;
#pragma unroll 10
                    for (int k4 = 0; k4 < 80; ++k4) {
                        float4 wv = Wh4f[(size_t)k4 * G4n + c];
                        float4 hv = h4[k4];
                        ax += wv.x * hv.x; ay += wv.y * hv.y;
                        az += wv.z * hv.z; aw += wv.w * hv.w;
                    }
                    gg_s[c] = ax + ay + az + aw;
                }
            }
            __syncthreads();   // dec_s + gg_s slice ready
        }
        // ---- 6: publish record {f slice, gg slice}, release ----
        if (tid < 20) {
            const int c0l = 2 * tid, c1l = 2 * tid + 1;
            const float* xprow = advance ? xpB : xpA;
            float f0v = xprow[c0l] + dec_s[c0l];
            float f1v = xprow[c1l] + dec_s[c1l];
            union { float f2[2]; ull u; } pk;
            pk.f2[0] = f0v > 0.0f ? f0v : 0.0f;
            pk.f2[1] = f1v > 0.0f ? f1v : 0.0f;
            AS(recF8 + m * 20 + tid, pk.u);
        }
        if (emit && tid >= 128 && tid < 208)
            AS(recG8 + m * 80 + (tid - 128), ((ull*)(gg_s + m * 160))[tid - 128]);
        __syncthreads();   // drains all waves' vmcnt before flag
        if (tid == 0) AS(flgb + m * 16, es + 1);
        prevEmit = emit; told = tnew; sold = sym2;
    }
    // ---- tail fill + lengths (member 0) ----
    if (m == 0) {
        for (int ss = s + tid; ss < Sn; ss += 256) {
            out[ss * Bn + b] = 1024.0f;
            out[Sn * Bn + ss * Bn + b] = 0.0f;
            out[2 * Sn * Bn + ss * Bn + b] = (float)told;
        }
        if (tid == 0) out[3 * Sn * Bn + b] = (float)lenacc;
    }
}

extern "C" void kernel_launch(void* const* d_in, const int* in_sizes, int n_in,
                              void* d_out, int out_size, void* d_ws, size_t ws_size,
                              hipStream_t stream) {
    (void)in_sizes; (void)n_in; (void)out_size; (void)ws_size;
    const float* x      = (const float*)d_in[0];
    const int*   outlen = (const int*)d_in[1];
    const float* W_enc  = (const float*)d_in[2];
    const float* b_enc  = (const float*)d_in[3];
    const float* Emb    = (const float*)d_in[4];
    const float* W_ih   = (const float*)d_in[5];
    const float* W_hh   = (const float*)d_in[6];
    const float* b_lstm = (const float*)d_in[7];
    const float* W_pred = (const float*)d_in[8];
    const float* b_pred = (const float*)d_in[9];
    const float* W_out  = (const float*)d_in[10];
    const float* b_out  = (const float*)d_in[11];

    float* ws   = (float*)d_ws;
    float* xp   = ws + OFF_XP;
    float* Gm   = ws + OFF_G;
    float* Wo4  = ws + OFF_WO4;
    float* Wh4  = ws + OFF_WH4;
    float* Wp4  = ws + OFF_WP4;
    float* recF = ws + OFF_RECF;
    float* recG = ws + OFF_RECG;
    ull*   keyG = (ull*)(ws + OFF_KEY);
    int*   flgG = (int*)(ws + OFF_FLG);

    // reset sync state (keys + flags) every launch/replay
    hipMemsetAsync(keyG, 0, (4096 + 4096) * sizeof(float), stream);

    gemm_bias<<<dim3(5, 32), 256, 0, stream>>>(x, W_enc, b_enc, xp, Bn * Tn, Jn, 1024);
    gemm_bias<<<dim3(20, 16), 256, 0, stream>>>(Emb, W_ih, b_lstm, Gm, Vn, G4n, Hn);
    repack_wout4<<<80, 256, 0, stream>>>(W_out, Wo4);
    repack_whh4<<<80, 256, 0, stream>>>(W_hh, Wh4);
    repack_wpred4<<<80, 256, 0, stream>>>(W_pred, Wp4);

    rnnt_decode<<<256, 256, 0, stream>>>(xp, Gm, Wo4, Wh4, Wp4,
                                         b_out, b_lstm, b_pred, outlen,
                                         recF, recG, keyG, flgG, (float*)d_out);
}

// Round 10
// 3320.207 us; speedup vs baseline: 1.1184x; 1.1184x over previous
//
#include <hip/hip_runtime.h>
#include <math.h>

typedef unsigned long long ull;
typedef unsigned uint4v __attribute__((ext_vector_type(4)));

constexpr int Bn = 32, Tn = 64, Hn = 320, Jn = 320, Vn = 1024, Sn = 128;
constexpr int G4n = 1280, VP1 = 1025, WO4S = 1028;

// workspace layout (float units) -- ~12.0 MB
constexpr int OFF_XP   = 0;                       // 32*64*320
constexpr int OFF_G    = OFF_XP + Bn*Tn*Jn;       // 1024*1280
constexpr int OFF_WO4  = OFF_G + Vn*G4n;          // 80*1028*4
constexpr int OFF_WH4  = OFF_WO4 + 80*WO4S*4;     // 80*1280*4
constexpr int OFF_WP4  = OFF_WH4 + 80*G4n*4;      // 80*320*4
constexpr int OFF_RECF = OFF_WP4 + 80*Jn*4;       // 32*320 ull = 20480 f (tagged f atoms)
constexpr int OFF_RECG = OFF_RECF + 20480;        // 32*2*1280 ull = 163840 f (tagged gg atoms)
constexpr int OFF_KEY  = OFF_RECG + 163840;       // 32*32 ull = 2048 f
constexpr int MEMSET_FLOATS = 20480 + 163840 + 2048;

#define AL(p)    __hip_atomic_load((p), __ATOMIC_RELAXED, __HIP_MEMORY_SCOPE_AGENT)
#define AS(p, v) __hip_atomic_store((p), (v), __ATOMIC_RELAXED, __HIP_MEMORY_SCOPE_AGENT)

__device__ __forceinline__ float sigmf(float x) { return 1.0f / (1.0f + expf(-x)); }

// ---- transport: dual-publish (plain->local L2, sc1->L3), self-validating polls ----
__device__ __forceinline__ void st_plain_u64(ull* p, ull v) {
    asm volatile("global_store_dwordx2 %0, %1, off" :: "v"(p), "v"(v) : "memory");
}
__device__ __forceinline__ void st2_u64(ull* p, ull v) {
    st_plain_u64(p, v);   // intra-XCD fast copy (write-through to this XCD's L2)
    AS(p, v);             // agent copy (L3) -- guaranteed liveness channel
}
__device__ __forceinline__ ull ld_sc0_u64(const ull* p) {
    ull v;
    asm volatile("global_load_dwordx2 %0, %1, off sc0\n\ts_waitcnt vmcnt(0)"
                 : "=v"(v) : "v"(p) : "memory");
    return v;
}
__device__ __forceinline__ uint4v ld_sc0_b128(const ull* p) {
    uint4v v;
    asm volatile("global_load_dwordx4 %0, %1, off sc0\n\ts_waitcnt vmcnt(0)"
                 : "=v"(v) : "v"(p) : "memory");
    return v;
}
__device__ __forceinline__ void ld4_sc0(const ull* p0, const ull* p1,
                                        const ull* p2, const ull* p3,
                                        ull& a0, ull& a1, ull& a2, ull& a3) {
    asm volatile("global_load_dwordx2 %0, %4, off sc0\n\t"
                 "global_load_dwordx2 %1, %5, off sc0\n\t"
                 "global_load_dwordx2 %2, %6, off sc0\n\t"
                 "global_load_dwordx2 %3, %7, off sc0\n\t"
                 "s_waitcnt vmcnt(0)"
                 : "=&v"(a0), "=&v"(a1), "=&v"(a2), "=&v"(a3)
                 : "v"(p0), "v"(p1), "v"(p2), "v"(p3)
                 : "memory");
}
// alternate sc0 / sc1 until tag satisfied (liveness via sc1; speed via sc0)
__device__ __forceinline__ float poll_atom_f(const ull* p, unsigned need) {
    for (;;) {
        ull a = ld_sc0_u64(p);
        if ((unsigned)(a >> 32) >= need) return __uint_as_float((unsigned)a);
        a = AL(p);
        if ((unsigned)(a >> 32) >= need) return __uint_as_float((unsigned)a);
        __builtin_amdgcn_s_sleep(1);
    }
}

// key = mapped_val(32) | epoch(21 bits) | (2047-idx)(11 bits)
__device__ __forceinline__ ull pack_key_e(float v, int idx, int es) {
    unsigned u = __float_as_uint(v);
    u = (u & 0x80000000u) ? ~u : (u | 0x80000000u);
    return ((ull)u << 32) | ((ull)(unsigned)es << 11) | (unsigned)(2047 - idx);
}
__device__ __forceinline__ float key_val_e(ull k) {
    unsigned u = (unsigned)(k >> 32);
    return __uint_as_float((u & 0x80000000u) ? (u & 0x7FFFFFFFu) : ~u);
}
__device__ __forceinline__ int key_idx_e(ull k) { return 2047 - (int)(k & 0x7FF); }
__device__ __forceinline__ int key_ep_e(ull k)  { return (int)((k >> 11) & 0x1FFFFF); }
__device__ __forceinline__ ull poll_key(const ull* p, int es) {
    for (;;) {
        ull k = ld_sc0_u64(p);
        if (key_ep_e(k) >= es) return k;
        k = AL(p);
        if (key_ep_e(k) >= es) return k;
        __builtin_amdgcn_s_sleep(1);
    }
}

// ---------------- generic tiled f32 GEMM: C = A@B + bias ----------------
__global__ __launch_bounds__(256) void gemm_bias(const float* __restrict__ A,
                                                 const float* __restrict__ Bm,
                                                 const float* __restrict__ bias,
                                                 float* __restrict__ C,
                                                 int M, int N, int K) {
    __shared__ float As[16][65];
    __shared__ float Bs[16][65];
    const int tx = threadIdx.x & 15, ty = threadIdx.x >> 4;
    const int n0 = blockIdx.x * 64, m0 = blockIdx.y * 64;
    float acc[4][4] = {};
    for (int k0 = 0; k0 < K; k0 += 16) {
        for (int i = threadIdx.x; i < 1024; i += 256) {
            int mm = i >> 4, kk = i & 15;
            As[kk][mm] = A[(m0 + mm) * K + k0 + kk];
            int kk2 = i >> 6, nn = i & 63;
            Bs[kk2][nn] = Bm[(k0 + kk2) * N + n0 + nn];
        }
        __syncthreads();
#pragma unroll
        for (int kk = 0; kk < 16; ++kk) {
            float av[4], bv[4];
#pragma unroll
            for (int r = 0; r < 4; ++r) { av[r] = As[kk][ty * 4 + r]; bv[r] = Bs[kk][tx * 4 + r]; }
#pragma unroll
            for (int i2 = 0; i2 < 4; ++i2)
#pragma unroll
                for (int j2 = 0; j2 < 4; ++j2) acc[i2][j2] += av[i2] * bv[j2];
        }
        __syncthreads();
    }
#pragma unroll
    for (int i2 = 0; i2 < 4; ++i2)
#pragma unroll
        for (int j2 = 0; j2 < 4; ++j2)
            C[(m0 + ty * 4 + i2) * N + n0 + tx * 4 + j2] = acc[i2][j2] + bias[n0 + tx * 4 + j2];
}

// ---------------- k4-interleave repacks: W4[k/4][col][4] = W[k][col] ----------------
__global__ __launch_bounds__(256) void repack_wout4(const float* __restrict__ W,
                                                    float* __restrict__ W4) {
    const int k4 = blockIdx.x;
    for (int c = threadIdx.x; c < VP1; c += 256) {
        float4 v;
        v.x = W[(k4 * 4 + 0) * VP1 + c];
        v.y = W[(k4 * 4 + 1) * VP1 + c];
        v.z = W[(k4 * 4 + 2) * VP1 + c];
        v.w = W[(k4 * 4 + 3) * VP1 + c];
        ((float4*)W4)[(size_t)k4 * WO4S + c] = v;
    }
}
__global__ __launch_bounds__(256) void repack_whh4(const float* __restrict__ W,
                                                   float* __restrict__ W4) {
    const int k4 = blockIdx.x;
    for (int c = threadIdx.x; c < G4n; c += 256) {
        float4 v;
        v.x = W[(k4 * 4 + 0) * G4n + c];
        v.y = W[(k4 * 4 + 1) * G4n + c];
        v.z = W[(k4 * 4 + 2) * G4n + c];
        v.w = W[(k4 * 4 + 3) * G4n + c];
        ((float4*)W4)[(size_t)k4 * G4n + c] = v;
    }
}
__global__ __launch_bounds__(256) void repack_wpred4(const float* __restrict__ W,
                                                     float* __restrict__ W4) {
    const int k4 = blockIdx.x;
    for (int c = threadIdx.x; c < Jn; c += 256) {
        float4 v;
        v.x = W[(k4 * 4 + 0) * Jn + c];
        v.y = W[(k4 * 4 + 1) * Jn + c];
        v.z = W[(k4 * 4 + 2) * Jn + c];
        v.w = W[(k4 * 4 + 3) * Jn + c];
        ((float4*)W4)[(size_t)k4 * Jn + c] = v;
    }
}

// ---------------- decode: 8 WGs per batch element, tagged-atom dataflow ----------------
__global__ __launch_bounds__(256, 1) void rnnt_decode(
    const float* __restrict__ xp, const float* __restrict__ Gm,
    const float* __restrict__ Wo4, const float* __restrict__ Wh4,
    const float* __restrict__ Wp4,
    const float* __restrict__ b_out, const float* __restrict__ b_lstm,
    const float* __restrict__ b_pred, const int* __restrict__ out_len,
    ull* __restrict__ recF, ull* __restrict__ recG, ull* __restrict__ keyG,
    float* __restrict__ out) {
    __shared__ __align__(16) float f_s[Jn];
    __shared__ __align__(16) float h_s[Hn];
    __shared__ float c_s[Hn];
    __shared__ float dec_s[40];
    __shared__ ull bk_s;

    const int w = blockIdx.x, tid = threadIdx.x;
    const int b = w & 31, m = w >> 5;
    const int ol = out_len[b];
    const float* xpb = xp + b * Tn * Jn;
    ull* recF8 = recF + (size_t)b * Jn;          // 320 tagged f atoms
    ull* recG8 = recG + (size_t)b * 2 * G4n;     // 2 x 1280 tagged gg atoms
    ull* keysb = keyG + b * 32;                  // 17 key slots

    const float4* Wo4f = (const float4*)Wo4;
    const float4* Wh4f = (const float4*)Wh4;
    const float4* Wp4f = (const float4*)Wp4;
    const float4* h4 = (const float4*)h_s;
    const float4* f4 = (const float4*)f_s;

    // ==== prologue (replicated): h0, c0, dec0 -> f0 local; own dec slice cached ====
    for (int r = tid; r < Hn; r += 256) {
        float c0 = sigmf(b_lstm[r]) * tanhf(b_lstm[2 * Hn + r]);
        float h0 = sigmf(b_lstm[3 * Hn + r]) * tanhf(c0);
        c_s[r] = c0; h_s[r] = h0;
    }
    __syncthreads();
    for (int c = tid; c < Jn; c += 256) {
        float ax = 0.f, ay = 0.f, az = 0.f, aw = 0.f;
#pragma unroll 10
        for (int k4 = 0; k4 < 80; ++k4) {
            float4 wv = Wp4f[(size_t)k4 * Jn + c];
            float4 hv = h4[k4];
            ax += wv.x * hv.x; ay += wv.y * hv.y;
            az += wv.z * hv.z; aw += wv.w * hv.w;
        }
        float d = b_pred[c] + ax + ay + az + aw;
        float fv = xpb[c] + d;
        f_s[c] = fv > 0.0f ? fv : 0.0f;
        int lc = c - m * 40;
        if (lc >= 0 && lc < 40) dec_s[lc] = d;
    }
    __syncthreads();

    // ==== step loop ====
    int told = 0, sold = 0, lenacc = 0, q = 1;
    unsigned g = 0;
    bool hdirty = true;
    int s = 0;
    for (; s < Sn; ++s) {
        if (told >= ol) break;
        const int es = s + 1;
        // ---- A1: gates GEMV from local h (waves 2,3 + 32 helpers), tagged publish ----
        if (hdirty) { q ^= 1; ++g; }
        ull* gq = recG8 + (size_t)q * G4n;
        if (hdirty) {
            int ci = (tid >= 128) ? (tid - 128) : (tid < 32 ? 128 + tid : -1);
            if (ci >= 0) {
                const int c = m * 160 + ci;
                float ax = 0.f, ay = 0.f, az = 0.f, aw = 0.f;
#pragma unroll 20
                for (int k4 = 0; k4 < 80; ++k4) {
                    float4 wv = Wh4f[(size_t)k4 * G4n + c];
                    float4 hv = h4[k4];
                    ax += wv.x * hv.x; ay += wv.y * hv.y;
                    az += wv.z * hv.z; aw += wv.w * hv.w;
                }
                float a = ax + ay + az + aw;
                st2_u64(gq + c, ((ull)g << 32) | __float_as_uint(a));
            }
        }
        // ---- A2: f atoms poll (pairs via 16B sc0 load; per-atom fallback) ----
        if (s > 0) {
            if (tid < 160) {
                const ull* p = recF8 + 2 * tid;
                uint4v v = ld_sc0_b128(p);
                float v0 = (v.y >= (unsigned)es) ? __uint_as_float(v.x) : poll_atom_f(p, es);
                float v1 = (v.w >= (unsigned)es) ? __uint_as_float(v.z) : poll_atom_f(p + 1, es);
                f_s[2 * tid] = v0;
                f_s[2 * tid + 1] = v1;
            }
        }
        __syncthreads();   // f_s ready
        // ---- A3 (m==7, wave 3): blank column 1024 ----
        if (m == 7 && tid >= 192) {
            const int l = tid - 192;
            float4 wv = Wo4f[(size_t)l * WO4S + Vn];
            float4 fv = f4[l];
            float p = wv.x * fv.x + wv.y * fv.y + wv.z * fv.z + wv.w * fv.w;
            if (l < 16) {
                float4 wv2 = Wo4f[(size_t)(64 + l) * WO4S + Vn];
                float4 fv2 = f4[64 + l];
                p += wv2.x * fv2.x + wv2.y * fv2.y + wv2.z * fv2.z + wv2.w * fv2.w;
            }
#pragma unroll
            for (int d = 1; d < 64; d <<= 1) p += __shfl_xor(p, d, 64);
            if (l == 0) st2_u64(keysb + 16, pack_key_e(p + b_out[Vn], Vn, es));
        }
        // ---- A4: logits GEMV (128 cols) + key publish ----
        if (tid < 128) {
            const int c = m * 128 + tid;
            float ax = 0.f, ay = 0.f, az = 0.f, aw = 0.f;
#pragma unroll 20
            for (int k4 = 0; k4 < 80; ++k4) {
                float4 wv = Wo4f[(size_t)k4 * WO4S + c];
                float4 fv = f4[k4];
                ax += wv.x * fv.x; ay += wv.y * fv.y;
                az += wv.z * fv.z; aw += wv.w * fv.w;
            }
            ull key = pack_key_e(ax + ay + az + aw + b_out[c], c, es);
#pragma unroll
            for (int d = 1; d < 64; d <<= 1) {
                ull o = __shfl_xor(key, d, 64);
                if (o > key) key = o;
            }
            if ((tid & 63) == 0) st2_u64(keysb + m * 2 + (tid >> 6), key);
        }
        // ---- B: wave0 polls 17 keys, reduce ----
        if (tid < 64) {
            ull k = 0;
            if (tid < 17) k = poll_key(keysb + tid, es);
#pragma unroll
            for (int d = 1; d < 64; d <<= 1) {
                ull o = __shfl_xor(k, d, 64);
                if (o > k) k = o;
            }
            if (tid == 0) bk_s = k;
        }
        __syncthreads();
        const ull bk = bk_s;
        const int label = key_idx_e(bk);
        const bool emit = (label != Vn);
        int sym2 = emit ? sold + 1 : 0;
        const bool force = emit && (sym2 >= 2);
        const bool advance = (!emit) || force;
        const int tnew = told + (advance ? 1 : 0);
        sym2 = advance ? 0 : sym2;
        if (m == 0 && tid == 0) {
            out[s * Bn + b] = emit ? (float)label : 1024.0f;
            out[Sn * Bn + s * Bn + b] = key_val_e(bk);
            out[2 * Sn * Bn + s * Bn + b] = (float)told;
            if (emit) lenacc++;
        }
        // ---- LSTM (emit): per-thread tagged gg atom reads ----
        if (emit) {
            const float* gE = Gm + (size_t)label * G4n;
#pragma unroll 2
            for (int rr = 0; rr < 2; ++rr) {
                int r = tid + rr * 256;
                if (r < Hn) {
                    ull a0, a1, a2, a3;
                    ld4_sc0(gq + r, gq + Hn + r, gq + 2 * Hn + r, gq + 3 * Hn + r,
                            a0, a1, a2, a3);
                    float xi = ((unsigned)(a0 >> 32) >= g) ? __uint_as_float((unsigned)a0)
                                                           : poll_atom_f(gq + r, g);
                    float xf = ((unsigned)(a1 >> 32) >= g) ? __uint_as_float((unsigned)a1)
                                                           : poll_atom_f(gq + Hn + r, g);
                    float xg = ((unsigned)(a2 >> 32) >= g) ? __uint_as_float((unsigned)a2)
                                                           : poll_atom_f(gq + 2 * Hn + r, g);
                    float xo = ((unsigned)(a3 >> 32) >= g) ? __uint_as_float((unsigned)a3)
                                                           : poll_atom_f(gq + 3 * Hn + r, g);
                    xi += gE[r]; xf += gE[Hn + r]; xg += gE[2 * Hn + r]; xo += gE[3 * Hn + r];
                    float c2 = sigmf(xf) * c_s[r] + sigmf(xi) * tanhf(xg);
                    float h2 = sigmf(xo) * tanhf(c2);
                    c_s[r] = c2; h_s[r] = h2;
                }
            }
        }
        __syncthreads();   // h_s complete
        // ---- dec GEMV (own 40 cols, emit only; 2 threads/col k-split) ----
        if (emit && tid < 80) {
            const int cl = tid >> 1, kh = tid & 1;
            const int c = m * 40 + cl;
            float ax = 0.f, ay = 0.f, az = 0.f, aw = 0.f;
#pragma unroll 10
            for (int k4 = kh * 40; k4 < kh * 40 + 40; ++k4) {
                float4 wv = Wp4f[(size_t)k4 * Jn + c];
                float4 hv = h4[k4];
                ax += wv.x * hv.x; ay += wv.y * hv.y;
                az += wv.z * hv.z; aw += wv.w * hv.w;
            }
            float part = ax + ay + az + aw;
            part += __shfl_xor(part, 1, 64);
            if (kh == 0) dec_s[cl] = part + b_pred[c];
        }
        __syncthreads();   // dec_s ready
        // ---- publish own f slice (tagged atoms; tag s+2 for next step) ----
        if (tid < 40) {
            const int c = m * 40 + tid;
            const int tc = tnew < (Tn - 1) ? tnew : (Tn - 1);
            float fv = xpb[tc * Jn + c] + dec_s[tid];
            fv = fv > 0.0f ? fv : 0.0f;
            st2_u64(recF8 + c, ((ull)(unsigned)(s + 2) << 32) | __float_as_uint(fv));
        }
        hdirty = emit; told = tnew; sold = sym2;
    }
    // ---- tail fill + lengths (member 0) ----
    if (m == 0) {
        for (int ss = s + tid; ss < Sn; ss += 256) {
            out[ss * Bn + b] = 1024.0f;
            out[Sn * Bn + ss * Bn + b] = 0.0f;
            out[2 * Sn * Bn + ss * Bn + b] = (float)told;
        }
        if (tid == 0) out[3 * Sn * Bn + b] = (float)lenacc;
    }
}

extern "C" void kernel_launch(void* const* d_in, const int* in_sizes, int n_in,
                              void* d_out, int out_size, void* d_ws, size_t ws_size,
                              hipStream_t stream) {
    (void)in_sizes; (void)n_in; (void)out_size; (void)ws_size;
    const float* x      = (const float*)d_in[0];
    const int*   outlen = (const int*)d_in[1];
    const float* W_enc  = (const float*)d_in[2];
    const float* b_enc  = (const float*)d_in[3];
    const float* Emb    = (const float*)d_in[4];
    const float* W_ih   = (const float*)d_in[5];
    const float* W_hh   = (const float*)d_in[6];
    const float* b_lstm = (const float*)d_in[7];
    const float* W_pred = (const float*)d_in[8];
    const float* b_pred = (const float*)d_in[9];
    const float* W_out  = (const float*)d_in[10];
    const float* b_out  = (const float*)d_in[11];

    float* ws   = (float*)d_ws;
    float* xp   = ws + OFF_XP;
    float* Gm   = ws + OFF_G;
    float* Wo4  = ws + OFF_WO4;
    float* Wh4  = ws + OFF_WH4;
    float* Wp4  = ws + OFF_WP4;
    ull*   recF = (ull*)(ws + OFF_RECF);
    ull*   recG = (ull*)(ws + OFF_RECG);
    ull*   keyG = (ull*)(ws + OFF_KEY);

    // reset all tagged-atom state every launch/replay (tags restart at 0)
    hipMemsetAsync(recF, 0, (size_t)MEMSET_FLOATS * sizeof(float), stream);

    gemm_bias<<<dim3(5, 32), 256, 0, stream>>>(x, W_enc, b_enc, xp, Bn * Tn, Jn, 1024);
    gemm_bias<<<dim3(20, 16), 256, 0, stream>>>(Emb, W_ih, b_lstm, Gm, Vn, G4n, Hn);
    repack_wout4<<<80, 256, 0, stream>>>(W_out, Wo4);
    repack_whh4<<<80, 256, 0, stream>>>(W_hh, Wh4);
    repack_wpred4<<<80, 256, 0, stream>>>(W_pred, Wp4);

    rnnt_decode<<<256, 256, 0, stream>>>(xp, Gm, Wo4, Wh4, Wp4,
                                         b_out, b_lstm, b_pred, outlen,
                                         recF, recG, keyG, (float*)d_out);
}